// Round 7
// baseline (2220.049 us; speedup 1.0000x reference)
//
#include <hip/hip_runtime.h>

#define DIM 256
#define NEMB 8192
#define NQ 32768
#define OUT_Q_ELEMS 8388608   // 8*4096*256
#define NSEG 2
#define SEG_CODES 4096
#define CAP_H 24              // per (row, seg, wn-half) candidate capacity
#define MARGIN 1.0f

typedef __attribute__((ext_vector_type(8))) short short8;
typedef __attribute__((ext_vector_type(4))) float f32x4;
typedef unsigned int u32_as1 __attribute__((address_space(1)));
typedef unsigned int u32_as3 __attribute__((address_space(3)));

// fp32 -> bf16 round-to-nearest-even
__device__ __forceinline__ unsigned short f2bf(float f) {
    unsigned u = __float_as_uint(f);
    u += 0x7FFFu + ((u >> 16) & 1u);
    return (unsigned short)(u >> 16);
}
// async global->LDS, 16B per lane (dest = wave-uniform base + lane*16)
__device__ __forceinline__ void gll16(const void* g, void* l) {
    __builtin_amdgcn_global_load_lds((const u32_as1*)g, (u32_as3*)l, 16, 0, 0);
}

// The EXACT proven-passing metric: fp32 k-ascending single-accumulator fmaf
// chain, dist = ed[c] - 2*(double)dot. 2-deep pipelined 64B loads.
__device__ __forceinline__ double chain_dist(const float* __restrict__ ep,
                                             const float* __restrict__ xs,
                                             double edc) {
    float acc = 0.0f;
    float4 e0 = *(const float4*)(ep);
    float4 e1 = *(const float4*)(ep + 4);
    float4 e2 = *(const float4*)(ep + 8);
    float4 e3 = *(const float4*)(ep + 12);
#pragma unroll
    for (int kk = 0; kk < 15; ++kk) {
        const int k = kk * 16;
        float4 n0 = *(const float4*)(ep + k + 16);
        float4 n1 = *(const float4*)(ep + k + 20);
        float4 n2 = *(const float4*)(ep + k + 24);
        float4 n3 = *(const float4*)(ep + k + 28);
        float4 x0 = *(const float4*)(xs + k);
        float4 x1 = *(const float4*)(xs + k + 4);
        float4 x2 = *(const float4*)(xs + k + 8);
        float4 x3 = *(const float4*)(xs + k + 12);
        acc = fmaf(x0.x, e0.x, acc); acc = fmaf(x0.y, e0.y, acc);
        acc = fmaf(x0.z, e0.z, acc); acc = fmaf(x0.w, e0.w, acc);
        acc = fmaf(x1.x, e1.x, acc); acc = fmaf(x1.y, e1.y, acc);
        acc = fmaf(x1.z, e1.z, acc); acc = fmaf(x1.w, e1.w, acc);
        acc = fmaf(x2.x, e2.x, acc); acc = fmaf(x2.y, e2.y, acc);
        acc = fmaf(x2.z, e2.z, acc); acc = fmaf(x2.w, e2.w, acc);
        acc = fmaf(x3.x, e3.x, acc); acc = fmaf(x3.y, e3.y, acc);
        acc = fmaf(x3.z, e3.z, acc); acc = fmaf(x3.w, e3.w, acc);
        e0 = n0; e1 = n1; e2 = n2; e3 = n3;
    }
    {
        const int k = 240;
        float4 x0 = *(const float4*)(xs + k);
        float4 x1 = *(const float4*)(xs + k + 4);
        float4 x2 = *(const float4*)(xs + k + 8);
        float4 x3 = *(const float4*)(xs + k + 12);
        acc = fmaf(x0.x, e0.x, acc); acc = fmaf(x0.y, e0.y, acc);
        acc = fmaf(x0.z, e0.z, acc); acc = fmaf(x0.w, e0.w, acc);
        acc = fmaf(x1.x, e1.x, acc); acc = fmaf(x1.y, e1.y, acc);
        acc = fmaf(x1.z, e1.z, acc); acc = fmaf(x1.w, e1.w, acc);
        acc = fmaf(x2.x, e2.x, acc); acc = fmaf(x2.y, e2.y, acc);
        acc = fmaf(x2.z, e2.z, acc); acc = fmaf(x2.w, e2.w, acc);
        acc = fmaf(x3.x, e3.x, acc); acc = fmaf(x3.y, e3.y, acc);
        acc = fmaf(x3.z, e3.z, acc); acc = fmaf(x3.w, e3.w, acc);
    }
    return edc - 2.0 * (double)acc;
}

// ---------------------------------------------------------------------------
// Merged prep kernel, block ranges:
//   [0,512)      zero cnt2 (131072 ints)
//   [512,544)    enorm (fp64 + fp32 codebook norms)
//   [544,1056)   ebt   (embed^T via LDS-tiled transpose)
//   [1056,5152)  xc    (X -> bf16 LDS-image tiles)
//   [5152,6176)  ec    (E -> bf16 LDS-image tiles, transposed)
// ---------------------------------------------------------------------------
__global__ void prep_kernel(const float* __restrict__ input,
                            const float* __restrict__ embed,
                            int* __restrict__ cnt2, double* __restrict__ ed,
                            float* __restrict__ ef, float* __restrict__ ebt,
                            unsigned short* __restrict__ Xc,
                            unsigned short* __restrict__ Ec) {
    __shared__ float t[64][65];
    const int b = blockIdx.x;
    if (b < 512) {
        cnt2[b * 256 + threadIdx.x] = 0;
    } else if (b < 544) {
        int j = (b - 512) * 256 + threadIdx.x;
        double s = 0.0;
        for (int d = 0; d < DIM; ++d) {
            double v = (double)embed[(size_t)d * NEMB + j];
            s += v * v;
        }
        ed[j] = s;
        ef[j] = (float)s;
    } else if (b < 1056) {
        const int bb = b - 544;
        const int bx = bb & 127, by = bb >> 7;
        const int tx = threadIdx.x & 63, ty = threadIdx.x >> 6;
#pragma unroll
        for (int i = 0; i < 16; ++i) {
            int d = by * 64 + ty * 16 + i;
            t[ty * 16 + i][tx] = embed[(size_t)d * NEMB + bx * 64 + tx];
        }
        __syncthreads();
#pragma unroll
        for (int i = 0; i < 16; ++i) {
            int c = bx * 64 + ty * 16 + i;
            ebt[(size_t)c * DIM + by * 64 + tx] = t[tx][ty * 16 + i];
        }
    } else if (b < 5152) {
        int tid = (b - 1056) * 256 + threadIdx.x;  // NQ*32 units
        int q = tid >> 5, kcc = tid & 31;
        const float* p = input + (size_t)q * DIM + kcc * 8;
        float4 a = *(const float4*)p;
        float4 bv = *(const float4*)(p + 4);
        int mb = q >> 7, mrow = q & 127, kc = kcc >> 3, c = kcc & 7;
        short8 v;
        v[0] = (short)f2bf(a.x);  v[1] = (short)f2bf(a.y);
        v[2] = (short)f2bf(a.z);  v[3] = (short)f2bf(a.w);
        v[4] = (short)f2bf(bv.x); v[5] = (short)f2bf(bv.y);
        v[6] = (short)f2bf(bv.z); v[7] = (short)f2bf(bv.w);
        *(short8*)(Xc + (size_t)((((mb * 4 + kc) * 8) + c) * 128 + mrow) * 8) = v;
    } else {
        int tid = (b - 5152) * 256 + threadIdx.x;  // NEMB*32 units, n fast
        int n = tid & (NEMB - 1), kcc = tid >> 13;
        int nb = n >> 7, nrow = n & 127, kc = kcc >> 3, c = kcc & 7;
        short8 v;
#pragma unroll
        for (int j = 0; j < 8; ++j)
            v[j] = (short)f2bf(embed[(size_t)(kc * 64 + c * 8 + j) * NEMB + n]);
        *(short8*)(Ec + (size_t)((((nb * 4 + kc) * 8) + c) * 128 + nrow) * 8) = v;
    }
}

// ---------------------------------------------------------------------------
// MFMA argmin: block (mb, seg) owns 128 rows x 4096 codes (32 tiles).
// A-strip (64 KB, full K) LDS-resident; B streamed per-kc (16 KB) -> 80 KB,
// 2 blocks/CU, grid 512 = one clean round.
// Thin epilogue: s-space (s = x.e - ||e||^2/2, min-dist == max-s), lane-local
// running max, cross-lane reduce only every 4th tile (lagged threshold =
// conservative superset), one ballot/row-group fast path. No atomics.
// ---------------------------------------------------------------------------
__global__ __launch_bounds__(256, 2) void mfma_argmin_kernel(
    const unsigned short* __restrict__ Xc, const unsigned short* __restrict__ Ec,
    const float* __restrict__ ef, int* __restrict__ cnt2,
    unsigned short* __restrict__ cand) {
    __shared__ unsigned short As[32768];  // 64 KB: full-K A strip
    __shared__ unsigned short Bs[8192];   // 16 KB: one kc chunk of B

    const int tid = threadIdx.x;
    const int w = tid >> 6, l = tid & 63;
    const int wm = w >> 1, wn = w & 1;
    const int l15 = l & 15, q4 = l >> 4;
    const int mb = blockIdx.x & 255;
    const int seg = blockIdx.x >> 8;

    const unsigned short* xt = Xc + (size_t)mb * 4 * 8192;

    // ---- stage the whole A strip once (drained by the first Bs barrier)
#pragma unroll
    for (int s = 0; s < 16; ++s) {
        int t = w * 16 + s;
        gll16(xt + t * 512 + l * 8, &As[t * 512 + l * 8]);
    }

    float lmax[4][4];   // lane-local running max of s (per row-group)
    float tau[4][4];    // lagged collection threshold (s-space)
    int   rcnt[4][4];   // per row-group candidate count (uniform over l15)
#pragma unroll
    for (int i = 0; i < 4; ++i)
#pragma unroll
        for (int r = 0; r < 4; ++r) {
            lmax[i][r] = -1e30f; tau[i][r] = 1e30f; rcnt[i][r] = 0;
        }

    for (int t16 = 0; t16 < 32; ++t16) {
        const int nb = seg * 32 + t16;
        const unsigned short* et = Ec + (size_t)nb * 4 * 8192;
        const int col0 = nb * 128 + wn * 64 + l15;
        float enh[4];
#pragma unroll
        for (int j = 0; j < 4; ++j) enh[j] = 0.5f * ef[col0 + 16 * j];

        f32x4 acc[4][4];
#pragma unroll
        for (int i = 0; i < 4; ++i)
#pragma unroll
            for (int j = 0; j < 4; ++j) acc[i][j] = (f32x4){0.f, 0.f, 0.f, 0.f};

        for (int kc = 0; kc < 4; ++kc) {
            __syncthreads();
#pragma unroll
            for (int s = 0; s < 4; ++s) {
                int t = w * 4 + s;
                gll16(et + kc * 8192 + t * 512 + l * 8, &Bs[t * 512 + l * 8]);
            }
            __syncthreads();
#pragma unroll
            for (int ks = 0; ks < 2; ++ks) {
                short8 af[4], bf[4];
#pragma unroll
                for (int i = 0; i < 4; ++i)
                    af[i] = *(const short8*)&As[kc * 8192 +
                        ((ks * 4 + q4) * 128 + wm * 64 + i * 16 + l15) * 8];
#pragma unroll
                for (int j = 0; j < 4; ++j)
                    bf[j] = *(const short8*)&Bs[
                        ((ks * 4 + q4) * 128 + wn * 64 + j * 16 + l15) * 8];
#pragma unroll
                for (int i = 0; i < 4; ++i)
#pragma unroll
                    for (int j = 0; j < 4; ++j)
                        acc[i][j] = __builtin_amdgcn_mfma_f32_16x16x32_bf16(
                            af[i], bf[j], acc[i][j], 0, 0, 0);
            }
        }

        // ---- thin epilogue
        const bool doReduce = ((t16 & 3) == 0);
#pragma unroll
        for (int i = 0; i < 4; ++i)
#pragma unroll
            for (int r = 0; r < 4; ++r) {
                const float s0 = acc[i][0][r] - enh[0];
                const float s1 = acc[i][1][r] - enh[1];
                const float s2 = acc[i][2][r] - enh[2];
                const float s3 = acc[i][3][r] - enh[3];
                const float sm = fmaxf(fmaxf(s0, s1), fmaxf(s2, s3));
                lmax[i][r] = fmaxf(lmax[i][r], sm);
                if (doReduce) {
                    float M = lmax[i][r];
#pragma unroll
                    for (int step = 1; step < 16; step <<= 1)
                        M = fmaxf(M, __shfl_xor(M, step, 64));
                    tau[i][r] = M - 0.5f * MARGIN;
                }
                const unsigned long long bb = __ballot(sm > tau[i][r]);
                const unsigned g = (unsigned)(bb >> (q4 * 16)) & 0xFFFFu;
                if (g) {  // rare slow path: per-j allocation
                    int base = rcnt[i][r];
                    const int row128 = wm * 64 + i * 16 + q4 * 4 + r;
                    const size_t cb =
                        ((size_t)((mb * 128 + row128) * NSEG + seg) * 2 + wn) *
                        CAP_H;
                    const float sj[4] = {s0, s1, s2, s3};
#pragma unroll
                    for (int j = 0; j < 4; ++j) {
                        const bool cdd = sj[j] > tau[i][r];
                        const unsigned long long bj = __ballot(cdd);
                        const unsigned gj =
                            (unsigned)(bj >> (q4 * 16)) & 0xFFFFu;
                        if (cdd) {
                            int slot = base + __popc(gj & ((1u << l15) - 1u));
                            if (slot < CAP_H)
                                cand[cb + slot] =
                                    (unsigned short)(col0 + 16 * j);
                        }
                        base += __popc(gj);
                    }
                    rcnt[i][r] = base;
                }
            }
    }
    // ---- store per-(row,seg,half) counts (uniform over l15)
    if (l15 == 0) {
#pragma unroll
        for (int i = 0; i < 4; ++i)
#pragma unroll
            for (int r = 0; r < 4; ++r) {
                const int row128 = wm * 64 + i * 16 + q4 * 4 + r;
                cnt2[((mb * 128 + row128) * NSEG + seg) * 2 + wn] = rcnt[i][r];
            }
    }
}

// ---------------------------------------------------------------------------
// Rescore: merge the 4 per-(seg,half) lists; bit-exact proven-passing metric,
// smallest-index tie-break; bounded per-seg scan on overflow. Fused with
// quantize gather + fp64 diff partial. One wave per query.
// ---------------------------------------------------------------------------
__global__ __launch_bounds__(256) void rescore_kernel(
    const float* __restrict__ input, const float* __restrict__ ebt,
    const double* __restrict__ ed, const int* __restrict__ cnt2,
    const unsigned short* __restrict__ cand, float* __restrict__ out_q,
    float* __restrict__ out_idx, double* __restrict__ partials) {
    __shared__ float Xs[4][DIM];
    const int w = threadIdx.x >> 6, l = threadIdx.x & 63;
    const int q = blockIdx.x * 4 + w;
    const float* xs = Xs[w];

    float4 xf = *(const float4*)(input + (size_t)q * DIM + 4 * l);
    *(float4*)&Xs[w][4 * l] = xf;
    __syncthreads();

    int m[4];
    bool segscan[NSEG];
#pragma unroll
    for (int s2 = 0; s2 < NSEG; ++s2) segscan[s2] = false;
#pragma unroll
    for (int li = 0; li < 4; ++li) {
        int ns = cnt2[(q * NSEG + (li >> 1)) * 2 + (li & 1)];
        if (ns > CAP_H) segscan[li >> 1] = true;
        m[li] = ns;
    }
#pragma unroll
    for (int li = 0; li < 4; ++li)
        if (segscan[li >> 1]) m[li] = 0;  // seg scan supersedes its halves

    int tot = 0;
#pragma unroll
    for (int li = 0; li < 4; ++li) tot += m[li];

    double bd = 1e300;
    int bc = 0x7FFFFFFF;

    for (int base = 0; base < tot; base += 64) {
        const int idx = base + l;
        if (idx < tot) {
            int rem = idx, li = 0;
#pragma unroll
            for (int li2 = 0; li2 < 3; ++li2)
                if (rem >= m[li]) { rem -= m[li]; ++li; }
            const int c = cand[((size_t)(q * NSEG + (li >> 1)) * 2 + (li & 1))
                               * CAP_H + rem];
            double d = chain_dist(ebt + (size_t)c * DIM, xs, ed[c]);
            if (d < bd || (d == bd && c < bc)) { bd = d; bc = c; }
        }
    }
#pragma unroll
    for (int s2 = 0; s2 < NSEG; ++s2) {  // bounded fallback on overflow
        if (segscan[s2]) {
            for (int c = s2 * SEG_CODES + l; c < (s2 + 1) * SEG_CODES; c += 64) {
                double d = chain_dist(ebt + (size_t)c * DIM, xs, ed[c]);
                if (d < bd || (d == bd && c < bc)) { bd = d; bc = c; }
            }
        }
    }
#pragma unroll
    for (int off = 1; off < 64; off <<= 1) {
        double od = __shfl_xor(bd, off, 64);
        int oc = __shfl_xor(bc, off, 64);
        if (od < bd || (od == bd && oc < bc)) { bd = od; bc = oc; }
    }

    float4 e4 = *(const float4*)(ebt + (size_t)bc * DIM + 4 * l);
    *(float4*)(out_q + (size_t)q * DIM + 4 * l) = e4;
    float d0 = e4.x - xf.x, d1 = e4.y - xf.y;
    float d2 = e4.z - xf.z, d3 = e4.w - xf.w;
    double dd = (double)d0 * d0 + (double)d1 * d1 +
                (double)d2 * d2 + (double)d3 * d3;
#pragma unroll
    for (int off = 1; off < 64; off <<= 1) dd += __shfl_xor(dd, off, 64);
    if (l == 0) {
        out_idx[q] = (float)bc;
        partials[q] = dd;
    }
}

// ---------------------------------------------------------------------------
// reduce partials -> mean -> diff
// ---------------------------------------------------------------------------
__global__ void diff_kernel(const double* __restrict__ partials,
                            float* __restrict__ out_diff) {
    const int t = threadIdx.x;
    double s = 0.0;
    for (int i = t; i < NQ; i += 256) s += partials[i];
#pragma unroll
    for (int off = 32; off >= 1; off >>= 1) s += __shfl_down(s, off, 64);
    __shared__ double red[4];
    if ((t & 63) == 0) red[t >> 6] = s;
    __syncthreads();
    if (t == 0)
        out_diff[0] = (float)((red[0] + red[1] + red[2] + red[3]) /
                              (double)OUT_Q_ELEMS);
}

extern "C" void kernel_launch(void* const* d_in, const int* in_sizes, int n_in,
                              void* d_out, int out_size, void* d_ws,
                              size_t ws_size, hipStream_t stream) {
    const float* input = (const float*)d_in[0];  // [8,4096,256] fp32
    const float* embed = (const float*)d_in[1];  // [256,8192]  fp32

    float* out_q    = (float*)d_out;             // quantize
    float* out_diff = out_q + OUT_Q_ELEMS;       // diff scalar
    float* out_idx  = out_diff + 1;              // embed_ind (as float)

    char* p = (char*)d_ws;
    unsigned short* Ec  = (unsigned short*)(p);                 //  4 MB
    unsigned short* Xc  = (unsigned short*)(p + 4194304);       // 16 MB
    float*          ebt = (float*)(p + 20971520);               //  8 MB
    double*         ed  = (double*)(p + 29360128);              // 64 KB
    float*          ef  = (float*)(p + 29425664);               // 32 KB
    int*            cnt2 = (int*)(p + 29458432);                // 512 KB
    double*         partials = (double*)(p + 29982720);         // 256 KB
    unsigned short* cand = (unsigned short*)(p + 30244864);     //  6.3 MB

    hipLaunchKernelGGL(prep_kernel, dim3(6176), dim3(256), 0, stream,
                       input, embed, cnt2, ed, ef, ebt, Xc, Ec);
    hipLaunchKernelGGL(mfma_argmin_kernel, dim3((NQ / 128) * NSEG), dim3(256),
                       0, stream, Xc, Ec, ef, cnt2, cand);
    hipLaunchKernelGGL(rescore_kernel, dim3(NQ / 4), dim3(256), 0, stream,
                       input, ebt, ed, cnt2, cand, out_q, out_idx, partials);
    hipLaunchKernelGGL(diff_kernel, dim3(1), dim3(256), 0, stream,
                       partials, out_diff);
}

// Round 8
// 540.928 us; speedup vs baseline: 4.1042x; 4.1042x over previous
//
#include <hip/hip_runtime.h>

#define DIM 256
#define NEMB 8192
#define NQ 32768
#define OUT_Q_ELEMS 8388608   // 8*4096*256
#define NSEG 2
#define SEG_CODES 4096
#define CAP_H 32              // per (row, seg, wn-half) candidate capacity
#define MARGIN 1.0f

typedef __attribute__((ext_vector_type(8))) short short8;
typedef __attribute__((ext_vector_type(4))) float f32x4;
typedef unsigned int u32_as1 __attribute__((address_space(1)));
typedef unsigned int u32_as3 __attribute__((address_space(3)));

// fp32 -> bf16 round-to-nearest-even
__device__ __forceinline__ unsigned short f2bf(float f) {
    unsigned u = __float_as_uint(f);
    u += 0x7FFFu + ((u >> 16) & 1u);
    return (unsigned short)(u >> 16);
}
// async global->LDS, 16B per lane (dest = wave-uniform base + lane*16)
__device__ __forceinline__ void gll16(const void* g, void* l) {
    __builtin_amdgcn_global_load_lds((const u32_as1*)g, (u32_as3*)l, 16, 0, 0);
}

// The EXACT proven-passing metric: fp32 k-ascending single-accumulator fmaf
// chain, dist = ed[c] - 2*(double)dot. 2-deep pipelined 64B loads.
__device__ __forceinline__ double chain_dist(const float* __restrict__ ep,
                                             const float* __restrict__ xs,
                                             double edc) {
    float acc = 0.0f;
    float4 e0 = *(const float4*)(ep);
    float4 e1 = *(const float4*)(ep + 4);
    float4 e2 = *(const float4*)(ep + 8);
    float4 e3 = *(const float4*)(ep + 12);
#pragma unroll
    for (int kk = 0; kk < 15; ++kk) {
        const int k = kk * 16;
        float4 n0 = *(const float4*)(ep + k + 16);
        float4 n1 = *(const float4*)(ep + k + 20);
        float4 n2 = *(const float4*)(ep + k + 24);
        float4 n3 = *(const float4*)(ep + k + 28);
        float4 x0 = *(const float4*)(xs + k);
        float4 x1 = *(const float4*)(xs + k + 4);
        float4 x2 = *(const float4*)(xs + k + 8);
        float4 x3 = *(const float4*)(xs + k + 12);
        acc = fmaf(x0.x, e0.x, acc); acc = fmaf(x0.y, e0.y, acc);
        acc = fmaf(x0.z, e0.z, acc); acc = fmaf(x0.w, e0.w, acc);
        acc = fmaf(x1.x, e1.x, acc); acc = fmaf(x1.y, e1.y, acc);
        acc = fmaf(x1.z, e1.z, acc); acc = fmaf(x1.w, e1.w, acc);
        acc = fmaf(x2.x, e2.x, acc); acc = fmaf(x2.y, e2.y, acc);
        acc = fmaf(x2.z, e2.z, acc); acc = fmaf(x2.w, e2.w, acc);
        acc = fmaf(x3.x, e3.x, acc); acc = fmaf(x3.y, e3.y, acc);
        acc = fmaf(x3.z, e3.z, acc); acc = fmaf(x3.w, e3.w, acc);
        e0 = n0; e1 = n1; e2 = n2; e3 = n3;
    }
    {
        const int k = 240;
        float4 x0 = *(const float4*)(xs + k);
        float4 x1 = *(const float4*)(xs + k + 4);
        float4 x2 = *(const float4*)(xs + k + 8);
        float4 x3 = *(const float4*)(xs + k + 12);
        acc = fmaf(x0.x, e0.x, acc); acc = fmaf(x0.y, e0.y, acc);
        acc = fmaf(x0.z, e0.z, acc); acc = fmaf(x0.w, e0.w, acc);
        acc = fmaf(x1.x, e1.x, acc); acc = fmaf(x1.y, e1.y, acc);
        acc = fmaf(x1.z, e1.z, acc); acc = fmaf(x1.w, e1.w, acc);
        acc = fmaf(x2.x, e2.x, acc); acc = fmaf(x2.y, e2.y, acc);
        acc = fmaf(x2.z, e2.z, acc); acc = fmaf(x2.w, e2.w, acc);
        acc = fmaf(x3.x, e3.x, acc); acc = fmaf(x3.y, e3.y, acc);
        acc = fmaf(x3.z, e3.z, acc); acc = fmaf(x3.w, e3.w, acc);
    }
    return edc - 2.0 * (double)acc;
}

// ---------------------------------------------------------------------------
// Merged prep kernel, block ranges:
//   [0,512)      zero cnt2 (131072 ints)
//   [512,544)    enorm (fp64 + fp32 codebook norms)
//   [544,1056)   ebt   (embed^T via LDS-tiled transpose)
//   [1056,5152)  xc    (X -> bf16 LDS-image tiles)
//   [5152,6176)  ec    (E -> bf16 LDS-image tiles, transposed)
// ---------------------------------------------------------------------------
__global__ void prep_kernel(const float* __restrict__ input,
                            const float* __restrict__ embed,
                            int* __restrict__ cnt2, double* __restrict__ ed,
                            float* __restrict__ ef, float* __restrict__ ebt,
                            unsigned short* __restrict__ Xc,
                            unsigned short* __restrict__ Ec) {
    __shared__ float t[64][65];
    const int b = blockIdx.x;
    if (b < 512) {
        cnt2[b * 256 + threadIdx.x] = 0;
    } else if (b < 544) {
        int j = (b - 512) * 256 + threadIdx.x;
        double s = 0.0;
        for (int d = 0; d < DIM; ++d) {
            double v = (double)embed[(size_t)d * NEMB + j];
            s += v * v;
        }
        ed[j] = s;
        ef[j] = (float)s;
    } else if (b < 1056) {
        const int bb = b - 544;
        const int bx = bb & 127, by = bb >> 7;
        const int tx = threadIdx.x & 63, ty = threadIdx.x >> 6;
#pragma unroll
        for (int i = 0; i < 16; ++i) {
            int d = by * 64 + ty * 16 + i;
            t[ty * 16 + i][tx] = embed[(size_t)d * NEMB + bx * 64 + tx];
        }
        __syncthreads();
#pragma unroll
        for (int i = 0; i < 16; ++i) {
            int c = bx * 64 + ty * 16 + i;
            ebt[(size_t)c * DIM + by * 64 + tx] = t[tx][ty * 16 + i];
        }
    } else if (b < 5152) {
        int tid = (b - 1056) * 256 + threadIdx.x;  // NQ*32 units
        int q = tid >> 5, kcc = tid & 31;
        const float* p = input + (size_t)q * DIM + kcc * 8;
        float4 a = *(const float4*)p;
        float4 bv = *(const float4*)(p + 4);
        int mb = q >> 7, mrow = q & 127, kc = kcc >> 3, c = kcc & 7;
        short8 v;
        v[0] = (short)f2bf(a.x);  v[1] = (short)f2bf(a.y);
        v[2] = (short)f2bf(a.z);  v[3] = (short)f2bf(a.w);
        v[4] = (short)f2bf(bv.x); v[5] = (short)f2bf(bv.y);
        v[6] = (short)f2bf(bv.z); v[7] = (short)f2bf(bv.w);
        *(short8*)(Xc + (size_t)((((mb * 4 + kc) * 8) + c) * 128 + mrow) * 8) = v;
    } else {
        int tid = (b - 5152) * 256 + threadIdx.x;  // NEMB*32 units, n fast
        int n = tid & (NEMB - 1), kcc = tid >> 13;
        int nb = n >> 7, nrow = n & 127, kc = kcc >> 3, c = kcc & 7;
        short8 v;
#pragma unroll
        for (int j = 0; j < 8; ++j)
            v[j] = (short)f2bf(embed[(size_t)(kc * 64 + c * 8 + j) * NEMB + n]);
        *(short8*)(Ec + (size_t)((((nb * 4 + kc) * 8) + c) * 128 + nrow) * 8) = v;
    }
}

// ---------------------------------------------------------------------------
// MFMA argmin: block (mb, seg) owns 128 rows x 4096 codes (32 tiles).
// A-strip (64 KB, full K) LDS-resident; B streamed per-kc (16 KB) -> 80 KB,
// 2 blocks/CU, grid 512 = one clean round.
// Epilogue in s-space (s = x.e - ||e||^2/2; min-dist == max-s) with EXACT
// per-tile cross-lane threshold (lagged tau was round 7's overflow disaster);
// single-ballot fast path, ballot-prefix slot allocation. No atomics.
// ---------------------------------------------------------------------------
__global__ __launch_bounds__(256, 2) void mfma_argmin_kernel(
    const unsigned short* __restrict__ Xc, const unsigned short* __restrict__ Ec,
    const float* __restrict__ ef, int* __restrict__ cnt2,
    unsigned short* __restrict__ cand) {
    __shared__ unsigned short As[32768];  // 64 KB: full-K A strip
    __shared__ unsigned short Bs[8192];   // 16 KB: one kc chunk of B

    const int tid = threadIdx.x;
    const int w = tid >> 6, l = tid & 63;
    const int wm = w >> 1, wn = w & 1;
    const int l15 = l & 15, q4 = l >> 4;
    const int mb = blockIdx.x & 255;
    const int seg = blockIdx.x >> 8;

    const unsigned short* xt = Xc + (size_t)mb * 4 * 8192;

    // ---- stage the whole A strip once (drained by the first Bs barrier)
#pragma unroll
    for (int s = 0; s < 16; ++s) {
        int t = w * 16 + s;
        gll16(xt + t * 512 + l * 8, &As[t * 512 + l * 8]);
    }

    float rmax[4][4];   // cross-lane running max of s (per row-group), exact
    int   rcnt[4][4];   // per row-group candidate count (uniform over l15)
#pragma unroll
    for (int i = 0; i < 4; ++i)
#pragma unroll
        for (int r = 0; r < 4; ++r) { rmax[i][r] = -1e30f; rcnt[i][r] = 0; }

    for (int t16 = 0; t16 < 32; ++t16) {
        const int nb = seg * 32 + t16;
        const unsigned short* et = Ec + (size_t)nb * 4 * 8192;
        const int col0 = nb * 128 + wn * 64 + l15;
        float enh[4];
#pragma unroll
        for (int j = 0; j < 4; ++j) enh[j] = 0.5f * ef[col0 + 16 * j];

        f32x4 acc[4][4];
#pragma unroll
        for (int i = 0; i < 4; ++i)
#pragma unroll
            for (int j = 0; j < 4; ++j) acc[i][j] = (f32x4){0.f, 0.f, 0.f, 0.f};

        for (int kc = 0; kc < 4; ++kc) {
            __syncthreads();
#pragma unroll
            for (int s = 0; s < 4; ++s) {
                int t = w * 4 + s;
                gll16(et + kc * 8192 + t * 512 + l * 8, &Bs[t * 512 + l * 8]);
            }
            __syncthreads();
#pragma unroll
            for (int ks = 0; ks < 2; ++ks) {
                short8 af[4], bf[4];
#pragma unroll
                for (int i = 0; i < 4; ++i)
                    af[i] = *(const short8*)&As[kc * 8192 +
                        ((ks * 4 + q4) * 128 + wm * 64 + i * 16 + l15) * 8];
#pragma unroll
                for (int j = 0; j < 4; ++j)
                    bf[j] = *(const short8*)&Bs[
                        ((ks * 4 + q4) * 128 + wn * 64 + j * 16 + l15) * 8];
#pragma unroll
                for (int i = 0; i < 4; ++i)
#pragma unroll
                    for (int j = 0; j < 4; ++j)
                        acc[i][j] = __builtin_amdgcn_mfma_f32_16x16x32_bf16(
                            af[i], bf[j], acc[i][j], 0, 0, 0);
            }
        }

        // ---- epilogue: s-space, exact per-tile threshold, ballot collection
#pragma unroll
        for (int i = 0; i < 4; ++i)
#pragma unroll
            for (int r = 0; r < 4; ++r) {
                const float s0 = acc[i][0][r] - enh[0];
                const float s1 = acc[i][1][r] - enh[1];
                const float s2 = acc[i][2][r] - enh[2];
                const float s3 = acc[i][3][r] - enh[3];
                float M = fmaxf(fmaxf(fmaxf(s0, s1), fmaxf(s2, s3)),
                                rmax[i][r]);
#pragma unroll
                for (int step = 1; step < 16; step <<= 1)
                    M = fmaxf(M, __shfl_xor(M, step, 64));  // exact row max
                rmax[i][r] = M;
                const float tau = M - 0.5f * MARGIN;
                const float sm = fmaxf(fmaxf(s0, s1), fmaxf(s2, s3));
                const unsigned long long bb = __ballot(sm > tau);
                const unsigned g = (unsigned)(bb >> (q4 * 16)) & 0xFFFFu;
                if (g) {  // rare slow path: per-j allocation
                    int base = rcnt[i][r];
                    const int row128 = wm * 64 + i * 16 + q4 * 4 + r;
                    const size_t cb =
                        ((size_t)((mb * 128 + row128) * NSEG + seg) * 2 + wn) *
                        CAP_H;
                    const float sj[4] = {s0, s1, s2, s3};
#pragma unroll
                    for (int j = 0; j < 4; ++j) {
                        const bool cdd = sj[j] > tau;
                        const unsigned long long bj = __ballot(cdd);
                        const unsigned gj =
                            (unsigned)(bj >> (q4 * 16)) & 0xFFFFu;
                        if (cdd) {
                            int slot = base + __popc(gj & ((1u << l15) - 1u));
                            if (slot < CAP_H)
                                cand[cb + slot] =
                                    (unsigned short)(col0 + 16 * j);
                        }
                        base += __popc(gj);
                    }
                    rcnt[i][r] = base;
                }
            }
    }
    // ---- store per-(row,seg,half) counts (uniform over l15)
    if (l15 == 0) {
#pragma unroll
        for (int i = 0; i < 4; ++i)
#pragma unroll
            for (int r = 0; r < 4; ++r) {
                const int row128 = wm * 64 + i * 16 + q4 * 4 + r;
                cnt2[((mb * 128 + row128) * NSEG + seg) * 2 + wn] = rcnt[i][r];
            }
    }
}

// ---------------------------------------------------------------------------
// Rescore: merge the 4 per-(seg,half) lists; bit-exact proven-passing metric,
// smallest-index tie-break; bounded per-seg scan on overflow (P ~ 1e-6).
// Fused with quantize gather + fp64 diff partial. One wave per query.
// ---------------------------------------------------------------------------
__global__ __launch_bounds__(256) void rescore_kernel(
    const float* __restrict__ input, const float* __restrict__ ebt,
    const double* __restrict__ ed, const int* __restrict__ cnt2,
    const unsigned short* __restrict__ cand, float* __restrict__ out_q,
    float* __restrict__ out_idx, double* __restrict__ partials) {
    __shared__ float Xs[4][DIM];
    const int w = threadIdx.x >> 6, l = threadIdx.x & 63;
    const int q = blockIdx.x * 4 + w;
    const float* xs = Xs[w];

    float4 xf = *(const float4*)(input + (size_t)q * DIM + 4 * l);
    *(float4*)&Xs[w][4 * l] = xf;
    __syncthreads();

    int m[4];
    bool segscan[NSEG];
#pragma unroll
    for (int s2 = 0; s2 < NSEG; ++s2) segscan[s2] = false;
#pragma unroll
    for (int li = 0; li < 4; ++li) {
        int ns = cnt2[(q * NSEG + (li >> 1)) * 2 + (li & 1)];
        if (ns > CAP_H) segscan[li >> 1] = true;
        m[li] = ns;
    }
#pragma unroll
    for (int li = 0; li < 4; ++li)
        if (segscan[li >> 1]) m[li] = 0;  // seg scan supersedes its halves

    int tot = 0;
#pragma unroll
    for (int li = 0; li < 4; ++li) tot += m[li];

    double bd = 1e300;
    int bc = 0x7FFFFFFF;

    for (int base = 0; base < tot; base += 64) {
        const int idx = base + l;
        if (idx < tot) {
            int rem = idx, li = 0;
#pragma unroll
            for (int li2 = 0; li2 < 3; ++li2)
                if (rem >= m[li]) { rem -= m[li]; ++li; }
            const int c = cand[((size_t)(q * NSEG + (li >> 1)) * 2 + (li & 1))
                               * CAP_H + rem];
            double d = chain_dist(ebt + (size_t)c * DIM, xs, ed[c]);
            if (d < bd || (d == bd && c < bc)) { bd = d; bc = c; }
        }
    }
#pragma unroll
    for (int s2 = 0; s2 < NSEG; ++s2) {  // bounded fallback on overflow
        if (segscan[s2]) {
            for (int c = s2 * SEG_CODES + l; c < (s2 + 1) * SEG_CODES; c += 64) {
                double d = chain_dist(ebt + (size_t)c * DIM, xs, ed[c]);
                if (d < bd || (d == bd && c < bc)) { bd = d; bc = c; }
            }
        }
    }
#pragma unroll
    for (int off = 1; off < 64; off <<= 1) {
        double od = __shfl_xor(bd, off, 64);
        int oc = __shfl_xor(bc, off, 64);
        if (od < bd || (od == bd && oc < bc)) { bd = od; bc = oc; }
    }

    float4 e4 = *(const float4*)(ebt + (size_t)bc * DIM + 4 * l);
    *(float4*)(out_q + (size_t)q * DIM + 4 * l) = e4;
    float d0 = e4.x - xf.x, d1 = e4.y - xf.y;
    float d2 = e4.z - xf.z, d3 = e4.w - xf.w;
    double dd = (double)d0 * d0 + (double)d1 * d1 +
                (double)d2 * d2 + (double)d3 * d3;
#pragma unroll
    for (int off = 1; off < 64; off <<= 1) dd += __shfl_xor(dd, off, 64);
    if (l == 0) {
        out_idx[q] = (float)bc;
        partials[q] = dd;
    }
}

// ---------------------------------------------------------------------------
// reduce partials -> mean -> diff
// ---------------------------------------------------------------------------
__global__ void diff_kernel(const double* __restrict__ partials,
                            float* __restrict__ out_diff) {
    const int t = threadIdx.x;
    double s = 0.0;
    for (int i = t; i < NQ; i += 256) s += partials[i];
#pragma unroll
    for (int off = 32; off >= 1; off >>= 1) s += __shfl_down(s, off, 64);
    __shared__ double red[4];
    if ((t & 63) == 0) red[t >> 6] = s;
    __syncthreads();
    if (t == 0)
        out_diff[0] = (float)((red[0] + red[1] + red[2] + red[3]) /
                              (double)OUT_Q_ELEMS);
}

extern "C" void kernel_launch(void* const* d_in, const int* in_sizes, int n_in,
                              void* d_out, int out_size, void* d_ws,
                              size_t ws_size, hipStream_t stream) {
    const float* input = (const float*)d_in[0];  // [8,4096,256] fp32
    const float* embed = (const float*)d_in[1];  // [256,8192]  fp32

    float* out_q    = (float*)d_out;             // quantize
    float* out_diff = out_q + OUT_Q_ELEMS;       // diff scalar
    float* out_idx  = out_diff + 1;              // embed_ind (as float)

    char* p = (char*)d_ws;
    unsigned short* Ec  = (unsigned short*)(p);                 //  4 MB
    unsigned short* Xc  = (unsigned short*)(p + 4194304);       // 16 MB
    float*          ebt = (float*)(p + 20971520);               //  8 MB
    double*         ed  = (double*)(p + 29360128);              // 64 KB
    float*          ef  = (float*)(p + 29425664);               // 32 KB
    int*            cnt2 = (int*)(p + 29458432);                // 512 KB
    double*         partials = (double*)(p + 29982720);         // 256 KB
    unsigned short* cand = (unsigned short*)(p + 30244864);     //  8.4 MB

    hipLaunchKernelGGL(prep_kernel, dim3(6176), dim3(256), 0, stream,
                       input, embed, cnt2, ed, ef, ebt, Xc, Ec);
    hipLaunchKernelGGL(mfma_argmin_kernel, dim3((NQ / 128) * NSEG), dim3(256),
                       0, stream, Xc, Ec, ef, cnt2, cand);
    hipLaunchKernelGGL(rescore_kernel, dim3(NQ / 4), dim3(256), 0, stream,
                       input, ebt, ed, cnt2, cand, out_q, out_idx, partials);
    hipLaunchKernelGGL(diff_kernel, dim3(1), dim3(256), 0, stream,
                       partials, out_diff);
}